// Round 1
// baseline (92.754 us; speedup 1.0000x reference)
//
#include <hip/hip_runtime.h>

// Problem constants (match reference setup_inputs)
#define B_ 8
#define T_ 1024
#define S_ 4096
#define H_ 256

// K1: for each (b,s) find the largest tag index t with tag_to_token[b,t,s] > 0.
// Top-down scan with 8-row unroll (independent loads -> overlapped latency),
// early exit once found. Also histogram counts per (b,t).
__global__ void last_tag_kernel(const float* __restrict__ ttt,
                                int* __restrict__ L,
                                int* __restrict__ cnt) {
    int idx = blockIdx.x * blockDim.x + threadIdx.x;   // idx = b*S + s
    if (idx >= B_ * S_) return;
    int b = idx >> 12;          // / S_ (4096)
    int s = idx & (S_ - 1);
    const float* col = ttt + (size_t)b * T_ * S_ + s;

    int found = -1;
    for (int t0 = T_ - 8; t0 >= 0; t0 -= 8) {
        float v[8];
#pragma unroll
        for (int j = 0; j < 8; ++j)
            v[j] = col[(size_t)(t0 + j) * S_];
        int local = -1;
#pragma unroll
        for (int j = 0; j < 8; ++j)
            if (v[j] > 0.0f) local = j;    // ascending overwrite -> largest j
        if (local >= 0) { found = t0 + local; break; }
    }
    L[idx] = found;
    if (found >= 0) atomicAdd(&cnt[b * T_ + found], 1);
}

// K2: out[b,t,h] = seq_emb[t,h]  (float4 vectorized broadcast)
__global__ void init_out_kernel(const float* __restrict__ seq_emb,
                                float* __restrict__ out) {
    int i = blockIdx.x * blockDim.x + threadIdx.x;     // float4 index
    const int total4 = B_ * T_ * H_ / 4;
    if (i >= total4) return;
    int flat = i * 4;
    int h = flat & (H_ - 1);
    int t = (flat >> 8) & (T_ - 1);                    // (flat / H_) % T_
    float4 v = *reinterpret_cast<const float4*>(seq_emb + t * H_ + h);
    *reinterpret_cast<float4*>(out + (size_t)flat) = v;
}

// K3: scatter inputs[b,s,:] * (1/cnt[b,t]) into out[b,t,:], t = L[b,s].
// One block per (b,s); thread h handles hidden element h. Coalesced reads,
// ~4 atomic colliders per out cell for this data.
__global__ void scatter_kernel(const float* __restrict__ inputs,
                               const int* __restrict__ L,
                               const int* __restrict__ cnt,
                               float* __restrict__ out) {
    int bs = blockIdx.x;                               // b*S + s
    int t = L[bs];
    if (t < 0) return;
    int b = bs >> 12;
    float inv = 1.0f / (float)cnt[b * T_ + t];
    int h = threadIdx.x;
    float val = inputs[(size_t)bs * H_ + h] * inv;
    atomicAdd(out + ((size_t)(b * T_ + t) * H_ + h), val);
}

extern "C" void kernel_launch(void* const* d_in, const int* in_sizes, int n_in,
                              void* d_out, int out_size, void* d_ws, size_t ws_size,
                              hipStream_t stream) {
    const float* inputs  = (const float*)d_in[0];   // [B,S,H]
    const float* ttt     = (const float*)d_in[1];   // [B,T,S]
    const float* seq_emb = (const float*)d_in[2];   // [T,H]
    float* out = (float*)d_out;                     // [B,T,H]

    int* L   = (int*)d_ws;                          // B*S ints   (128 KiB)
    int* cnt = L + B_ * S_;                         // B*T ints   (32 KiB)

    hipMemsetAsync(cnt, 0, B_ * T_ * sizeof(int), stream);

    // K1: 32768 threads, 64-thread blocks -> 512 blocks spread across CUs
    last_tag_kernel<<<(B_ * S_ + 63) / 64, 64, 0, stream>>>(ttt, L, cnt);

    // K2: init out with seq_emb broadcast
    init_out_kernel<<<(B_ * T_ * H_ / 4 + 255) / 256, 256, 0, stream>>>(seq_emb, out);

    // K3: scatter-accumulate
    scatter_kernel<<<B_ * S_, H_, 0, stream>>>(inputs, L, cnt, out);
}

// Round 2
// 72.486 us; speedup vs baseline: 1.2796x; 1.2796x over previous
//
#include <hip/hip_runtime.h>

// Problem constants (match reference setup_inputs)
#define B_ 8
#define T_ 1024
#define S_ 4096
#define H_ 256

// K1: fully parallel "last covering tag" computation.
// Stream the [B,T,S] mask in layout order (coalesced float4); positives are
// rare (~0.2%), so resolve the max-over-t with atomicMax on L[b,s].
// L must be pre-initialized to -1 (0xFF memset).
__global__ void find_last_tag_stream(const float* __restrict__ ttt,
                                     int* __restrict__ L) {
    const long total4 = (long)B_ * T_ * S_ / 4;
    long stride = (long)gridDim.x * blockDim.x;
    for (long i = blockIdx.x * (long)blockDim.x + threadIdx.x; i < total4; i += stride) {
        float4 v = reinterpret_cast<const float4*>(ttt)[i];
        long flat = i * 4;                       // flat index into [b,t,s]
        int s = (int)(flat & (S_ - 1));          // low 12 bits
        int t = (int)((flat >> 12) & (T_ - 1));  // next 10 bits
        int b = (int)(flat >> 22);
        int* Lrow = L + b * S_ + s;
        if (v.x > 0.0f) atomicMax(Lrow + 0, t);
        if (v.y > 0.0f) atomicMax(Lrow + 1, t);
        if (v.z > 0.0f) atomicMax(Lrow + 2, t);
        if (v.w > 0.0f) atomicMax(Lrow + 3, t);
    }
}

// K2: scatter-accumulate unscaled sums: acc[b,t,:] += inputs[b,s,:] where
// t = L[b,s]; also count tokens per (b,t). One block per (b,s), thread = h.
__global__ void scatter_sum_kernel(const float* __restrict__ inputs,
                                   const int* __restrict__ L,
                                   float* __restrict__ acc,
                                   int* __restrict__ cnt) {
    int bs = blockIdx.x;                         // b*S + s
    int t = L[bs];
    if (t < 0) return;
    int b = bs >> 12;
    if (threadIdx.x == 0) atomicAdd(&cnt[b * T_ + t], 1);
    int h = threadIdx.x;
    float val = inputs[(size_t)bs * H_ + h];
    atomicAdd(acc + ((size_t)(b * T_ + t) * H_ + h), val);
}

// K3: out[b,t,h] = acc[b,t,h] / max(cnt[b,t],1) + seq_emb[t,h]  (in place, acc==out)
__global__ void normalize_kernel(float* __restrict__ out,
                                 const int* __restrict__ cnt,
                                 const float* __restrict__ seq_emb) {
    int i = blockIdx.x * blockDim.x + threadIdx.x;   // float4 index
    const int total4 = B_ * T_ * H_ / 4;
    if (i >= total4) return;
    int flat = i * 4;
    int h = flat & (H_ - 1);
    int t = (flat >> 8) & (T_ - 1);
    int b = flat >> 18;                              // flat / (T_*H_)
    int c = cnt[b * T_ + t];
    float inv = (c > 0) ? (1.0f / (float)c) : 1.0f;  // acc==0 when c==0
    float4 a = *reinterpret_cast<float4*>(out + flat);
    float4 e = *reinterpret_cast<const float4*>(seq_emb + t * H_ + h);
    a.x = a.x * inv + e.x;
    a.y = a.y * inv + e.y;
    a.z = a.z * inv + e.z;
    a.w = a.w * inv + e.w;
    *reinterpret_cast<float4*>(out + flat) = a;
}

extern "C" void kernel_launch(void* const* d_in, const int* in_sizes, int n_in,
                              void* d_out, int out_size, void* d_ws, size_t ws_size,
                              hipStream_t stream) {
    const float* inputs  = (const float*)d_in[0];   // [B,S,H]
    const float* ttt     = (const float*)d_in[1];   // [B,T,S]
    const float* seq_emb = (const float*)d_in[2];   // [T,H]
    float* out = (float*)d_out;                     // [B,T,H] — used as accumulator

    int* L   = (int*)d_ws;                          // B*S ints   (128 KiB)
    int* cnt = L + B_ * S_;                         // B*T ints   (32 KiB)

    hipMemsetAsync(L, 0xFF, B_ * S_ * sizeof(int), stream);   // L = -1
    hipMemsetAsync(cnt, 0, B_ * T_ * sizeof(int), stream);
    hipMemsetAsync(out, 0, (size_t)B_ * T_ * H_ * sizeof(float), stream);

    // K1: stream the 128 MiB mask at full bandwidth
    find_last_tag_stream<<<8192, 256, 0, stream>>>(ttt, L);

    // K2: scatter-accumulate
    scatter_sum_kernel<<<B_ * S_, H_, 0, stream>>>(inputs, L, out, cnt);

    // K3: normalize + add seq_emb
    normalize_kernel<<<(B_ * T_ * H_ / 4 + 255) / 256, 256, 0, stream>>>(out, cnt, seq_emb);
}

// Round 3
// 47.247 us; speedup vs baseline: 1.9632x; 1.5342x over previous
//
#include <hip/hip_runtime.h>

// Problem constants (match reference setup_inputs)
#define B_ 8
#define T_ 1024
#define S_ 4096
#define H_ 256
#define ROWS_PER_BLOCK 16

// K0: single init dispatch — out = 0 (float4), L = -1, cnt = 0.
// grid 2048 x 256 = 524288 threads = B*T*H/4 exactly.
__global__ void init_kernel(float* __restrict__ out,
                            int* __restrict__ L,
                            int* __restrict__ cnt) {
    int i = blockIdx.x * blockDim.x + threadIdx.x;
    float4 z = {0.0f, 0.0f, 0.0f, 0.0f};
    reinterpret_cast<float4*>(out)[i] = z;
    if (i < B_ * S_) L[i] = -1;
    if (i < B_ * T_) cnt[i] = 0;
}

// K1: fully parallel "last covering tag": stream the [B,T,S] mask in layout
// order (coalesced float4); positives are rare (~0.2%) -> atomicMax on L[b,s].
__global__ void find_last_tag_stream(const float* __restrict__ ttt,
                                     int* __restrict__ L) {
    const long total4 = (long)B_ * T_ * S_ / 4;
    long stride = (long)gridDim.x * blockDim.x;
    for (long i = blockIdx.x * (long)blockDim.x + threadIdx.x; i < total4; i += stride) {
        float4 v = reinterpret_cast<const float4*>(ttt)[i];
        long flat = i * 4;                       // flat index into [b,t,s]
        int s = (int)(flat & (S_ - 1));          // low 12 bits
        int t = (int)((flat >> 12) & (T_ - 1));  // next 10 bits
        int b = (int)(flat >> 22);
        int* Lrow = L + b * S_ + s;
        if (v.x > 0.0f) atomicMax(Lrow + 0, t);
        if (v.y > 0.0f) atomicMax(Lrow + 1, t);
        if (v.z > 0.0f) atomicMax(Lrow + 2, t);
        if (v.w > 0.0f) atomicMax(Lrow + 3, t);
    }
}

// K2: run-compressed scatter. One block per 16 consecutive tokens; thread h
// accumulates inputs[b,s,h] in a register while L[b,s] is unchanged, flushes
// with one atomicAdd per (run, h) on change. Counts accumulated per run.
// Branches are wave-uniform (t is uniform across the block).
__global__ void scatter_runs_kernel(const float* __restrict__ inputs,
                                    const int* __restrict__ L,
                                    float* __restrict__ acc,
                                    int* __restrict__ cnt) {
    int chunk = blockIdx.x;                          // b*(S/ROWS) + chunk
    int b = chunk / (S_ / ROWS_PER_BLOCK);
    int s0 = (chunk % (S_ / ROWS_PER_BLOCK)) * ROWS_PER_BLOCK;
    int h = threadIdx.x;
    const float* inp = inputs + ((size_t)b * S_ + s0) * H_ + h;
    const int* Lrow = L + b * S_ + s0;

    float a = 0.0f;
    int cur = -1, runlen = 0;
    for (int j = 0; j < ROWS_PER_BLOCK; ++j) {
        int t = Lrow[j];
        if (t != cur) {
            if (cur >= 0) {
                atomicAdd(acc + ((size_t)(b * T_ + cur) * H_ + h), a);
                if (h == 0) atomicAdd(&cnt[b * T_ + cur], runlen);
            }
            a = 0.0f; runlen = 0; cur = t;
        }
        if (t >= 0) { a += inp[(size_t)j * H_]; runlen++; }
    }
    if (cur >= 0) {
        atomicAdd(acc + ((size_t)(b * T_ + cur) * H_ + h), a);
        if (h == 0) atomicAdd(&cnt[b * T_ + cur], runlen);
    }
}

// K3: out[b,t,h] = acc[b,t,h] / max(cnt,1) + seq_emb[t,h]  (in place, acc==out)
__global__ void normalize_kernel(float* __restrict__ out,
                                 const int* __restrict__ cnt,
                                 const float* __restrict__ seq_emb) {
    int i = blockIdx.x * blockDim.x + threadIdx.x;   // float4 index
    const int total4 = B_ * T_ * H_ / 4;
    if (i >= total4) return;
    int flat = i * 4;
    int h = flat & (H_ - 1);
    int t = (flat >> 8) & (T_ - 1);
    int b = flat >> 18;                              // flat / (T_*H_)
    int c = cnt[b * T_ + t];
    float inv = (c > 0) ? (1.0f / (float)c) : 1.0f;  // acc==0 when c==0
    float4 a = *reinterpret_cast<float4*>(out + flat);
    float4 e = *reinterpret_cast<const float4*>(seq_emb + t * H_ + h);
    a.x = a.x * inv + e.x;
    a.y = a.y * inv + e.y;
    a.z = a.z * inv + e.z;
    a.w = a.w * inv + e.w;
    *reinterpret_cast<float4*>(out + flat) = a;
}

extern "C" void kernel_launch(void* const* d_in, const int* in_sizes, int n_in,
                              void* d_out, int out_size, void* d_ws, size_t ws_size,
                              hipStream_t stream) {
    const float* inputs  = (const float*)d_in[0];   // [B,S,H]
    const float* ttt     = (const float*)d_in[1];   // [B,T,S]
    const float* seq_emb = (const float*)d_in[2];   // [T,H]
    float* out = (float*)d_out;                     // [B,T,H] — also the accumulator

    int* L   = (int*)d_ws;                          // B*S ints   (128 KiB)
    int* cnt = L + B_ * S_;                         // B*T ints   (32 KiB)

    // K0: one init dispatch (out=0, L=-1, cnt=0)
    init_kernel<<<B_ * T_ * H_ / 4 / 256, 256, 0, stream>>>(out, L, cnt);

    // K1: stream the 128 MiB mask at full bandwidth
    find_last_tag_stream<<<8192, 256, 0, stream>>>(ttt, L);

    // K2: run-compressed scatter-accumulate
    scatter_runs_kernel<<<B_ * S_ / ROWS_PER_BLOCK, H_, 0, stream>>>(inputs, L, out, cnt);

    // K3: normalize + add seq_emb
    normalize_kernel<<<(B_ * T_ * H_ / 4 + 255) / 256, 256, 0, stream>>>(out, cnt, seq_emb);
}

// Round 4
// 42.001 us; speedup vs baseline: 2.2084x; 1.1249x over previous
//
#include <hip/hip_runtime.h>

// Problem constants (match reference setup_inputs)
#define B_ 8
#define T_ 1024
#define S_ 4096
#define H_ 256

// K0: L = -1 (int4 stores; 32768 ints = 128 KiB)
__global__ void init_L_kernel(int* __restrict__ L) {
    int i = blockIdx.x * blockDim.x + threadIdx.x;
    int4 m1 = {-1, -1, -1, -1};
    reinterpret_cast<int4*>(L)[i] = m1;
}

// K1: fully parallel "last covering tag": stream the [B,T,S] mask in layout
// order (coalesced float4); positives are rare (~0.2%) -> atomicMax on L[b,s].
__global__ void find_last_tag_stream(const float* __restrict__ ttt,
                                     int* __restrict__ L) {
    const long total4 = (long)B_ * T_ * S_ / 4;
    long stride = (long)gridDim.x * blockDim.x;
    for (long i = blockIdx.x * (long)blockDim.x + threadIdx.x; i < total4; i += stride) {
        float4 v = reinterpret_cast<const float4*>(ttt)[i];
        long flat = i * 4;                       // flat index into [b,t,s]
        int s = (int)(flat & (S_ - 1));          // low 12 bits
        int t = (int)((flat >> 12) & (T_ - 1));  // next 10 bits
        int b = (int)(flat >> 22);
        int* Lrow = L + b * S_ + s;
        if (v.x > 0.0f) atomicMax(Lrow + 0, t);
        if (v.y > 0.0f) atomicMax(Lrow + 1, t);
        if (v.z > 0.0f) atomicMax(Lrow + 2, t);
        if (v.w > 0.0f) atomicMax(Lrow + 3, t);
    }
}

// K2: gather + mean + seq_emb, fused. One wave per (b,t) output row.
// The wave scans L[b,:] with int4 loads (256 tokens / iteration via 4 ballots);
// for each matching token s, all 64 lanes accumulate the float4 slice of
// inputs[b,s,:] (1 KiB coalesced). No atomics, no zeroed accumulator.
__global__ void gather_mean_kernel(const float* __restrict__ inputs,
                                   const int* __restrict__ L,
                                   const float* __restrict__ seq_emb,
                                   float* __restrict__ out) {
    int wid  = threadIdx.x >> 6;
    int lane = threadIdx.x & 63;
    int bt = blockIdx.x * 4 + wid;               // (b*T + t), 4 waves per block
    int b = bt >> 10;                            // / T_
    int t = bt & (T_ - 1);

    const int4* Lb4 = reinterpret_cast<const int4*>(L + b * S_);
    const float4* in4 = reinterpret_cast<const float4*>(inputs);

    float4 acc = {0.0f, 0.0f, 0.0f, 0.0f};
    int c = 0;

#pragma unroll 4
    for (int c0 = 0; c0 < S_ / 4; c0 += 64) {    // int4 index space
        int4 v = Lb4[c0 + lane];
        unsigned long long m0 = __ballot(v.x == t);
        unsigned long long m1 = __ballot(v.y == t);
        unsigned long long m2 = __ballot(v.z == t);
        unsigned long long m3 = __ballot(v.w == t);
        while (m0) { int l = __ffsll(m0) - 1; m0 &= m0 - 1;
            int s = (c0 + l) * 4 + 0;
            float4 r = in4[(size_t)(b * S_ + s) * (H_ / 4) + lane];
            acc.x += r.x; acc.y += r.y; acc.z += r.z; acc.w += r.w; c++; }
        while (m1) { int l = __ffsll(m1) - 1; m1 &= m1 - 1;
            int s = (c0 + l) * 4 + 1;
            float4 r = in4[(size_t)(b * S_ + s) * (H_ / 4) + lane];
            acc.x += r.x; acc.y += r.y; acc.z += r.z; acc.w += r.w; c++; }
        while (m2) { int l = __ffsll(m2) - 1; m2 &= m2 - 1;
            int s = (c0 + l) * 4 + 2;
            float4 r = in4[(size_t)(b * S_ + s) * (H_ / 4) + lane];
            acc.x += r.x; acc.y += r.y; acc.z += r.z; acc.w += r.w; c++; }
        while (m3) { int l = __ffsll(m3) - 1; m3 &= m3 - 1;
            int s = (c0 + l) * 4 + 3;
            float4 r = in4[(size_t)(b * S_ + s) * (H_ / 4) + lane];
            acc.x += r.x; acc.y += r.y; acc.z += r.z; acc.w += r.w; c++; }
    }

    float inv = (c > 0) ? (1.0f / (float)c) : 0.0f;   // empty row -> just emb
    float4 e = reinterpret_cast<const float4*>(seq_emb)[t * (H_ / 4) + lane];
    float4 o;
    o.x = acc.x * inv + e.x;
    o.y = acc.y * inv + e.y;
    o.z = acc.z * inv + e.z;
    o.w = acc.w * inv + e.w;
    reinterpret_cast<float4*>(out)[(size_t)bt * (H_ / 4) + lane] = o;
}

extern "C" void kernel_launch(void* const* d_in, const int* in_sizes, int n_in,
                              void* d_out, int out_size, void* d_ws, size_t ws_size,
                              hipStream_t stream) {
    const float* inputs  = (const float*)d_in[0];   // [B,S,H]
    const float* ttt     = (const float*)d_in[1];   // [B,T,S]
    const float* seq_emb = (const float*)d_in[2];   // [T,H]
    float* out = (float*)d_out;                     // [B,T,H]

    int* L = (int*)d_ws;                            // B*S ints (128 KiB)

    // K0: L = -1  (32768 ints / (256 threads * 4 per thread) = 32 blocks)
    init_L_kernel<<<B_ * S_ / 4 / 256, 256, 0, stream>>>(L);

    // K1: stream the 128 MiB mask at full bandwidth
    find_last_tag_stream<<<8192, 256, 0, stream>>>(ttt, L);

    // K2: fused gather + mean + emb  (B*T/4 blocks, 1 wave per output row)
    gather_mean_kernel<<<B_ * T_ / 4, 256, 0, stream>>>(inputs, L, seq_emb, out);
}